// Round 16
// baseline (346.220 us; speedup 1.0000x reference)
//
#include <hip/hip_runtime.h>
#include <hip/hip_bf16.h>
#include <math.h>

#define N_NODES 100000
#define N_EDGES 1600000
#define HC 64          // H*C
#define NHEADS 2
#define NLAYERS 4
#define ECLS 5
#define NBUCK 196              // ceil(N / 512); bucket = dst >> 9
#define NBLK 256               // coarse pass blocks
#define EPB (N_EDGES / NBLK)   // 6250 edges per coarse block (exact)
#define NGRP (N_NODES / 16)    // 6250 16-node groups (exact)
#define LIN0_BLOCKS 1024

typedef __attribute__((ext_vector_type(8))) short short8;
typedef __attribute__((ext_vector_type(4))) float floatx4;
union F8 { uint4 u; short8 s; };

// bf16 (stored as ushort) -> f32
__device__ inline float bf_lo(unsigned int u) { return __uint_as_float(u << 16); }
__device__ inline float bf_hi(unsigned int u) { return __uint_as_float(u & 0xffff0000u); }
// f32 -> bf16 bits, round-to-nearest-even
__device__ inline unsigned short f2bf(float f) {
    unsigned int u = __float_as_uint(f);
    u += 0x7FFFu + ((u >> 16) & 1u);
    return (unsigned short)(u >> 16);
}

// ---------------- CSR P1 + layer-0 linear (merged: independent work) -------
__global__ void k_chist_lin0(const int* __restrict__ dst, int* __restrict__ bh,
                             const float* __restrict__ in,
                             const float* __restrict__ W,        // [4][64]
                             const float* __restrict__ asrc, const float* __restrict__ adst,
                             unsigned short* __restrict__ hcurb,
                             float* __restrict__ ssrc, float* __restrict__ sdst) {
    int tid = threadIdx.x;
    if (blockIdx.x < NBLK) {
        __shared__ int lh[NBUCK];
        int blk = blockIdx.x;
        for (int i = tid; i < NBUCK; i += 256) lh[i] = 0;
        __syncthreads();
        int s = blk * EPB, e = s + EPB;
        for (int i = s + tid; i < e; i += 256) atomicAdd(&lh[dst[i] >> 9], 1);
        __syncthreads();
        for (int i = tid; i < NBUCK; i += 256) bh[i * 256 + blk] = lh[i];
        return;
    }
    int j = tid & 63;
    int wid = ((blockIdx.x - NBLK) * 256 + tid) >> 6;
    int nwaves = LIN0_BLOCKS * 4;

    float w0 = W[0 * HC + j], w1 = W[1 * HC + j], w2 = W[2 * HC + j], w3 = W[3 * HC + j];
    int head = j >> 5;
    int c = j & 31;
    float as = asrc[head * 32 + c];
    float ad = adst[head * 32 + c];

    for (int n = wid; n < N_NODES; n += nwaves) {
        int nu = __builtin_amdgcn_readfirstlane(n);
        float4 r = *(const float4*)(in + (size_t)nu * 4);
        float acc = r.x * w0 + r.y * w1 + r.z * w2 + r.w * w3;
        hcurb[(size_t)nu * HC + j] = f2bf(acc);
        float ps = acc * as;
        float pd = acc * ad;
        for (int off = 16; off > 0; off >>= 1) {
            ps += __shfl_down(ps, off, 32);
            pd += __shfl_down(pd, off, 32);
        }
        if (c == 0) {
            ssrc[nu * 2 + head] = ps;
            sdst[nu * 2 + head] = pd;
        }
    }
}

__global__ void k_s1(const int* __restrict__ bh, int* __restrict__ bbase,
                     int* __restrict__ part) {
    __shared__ int tmp[256];
    int tid = threadIdx.x;
    int i = blockIdx.x * 256 + tid;
    int v = bh[i];
    tmp[tid] = v;
    __syncthreads();
    for (int off = 1; off < 256; off <<= 1) {
        int t = (tid >= off) ? tmp[tid - off] : 0;
        __syncthreads();
        tmp[tid] += t;
        __syncthreads();
    }
    bbase[i] = tmp[tid] - v;
    if (tid == 255) part[blockIdx.x] = tmp[255];
}

// exclusive scan of bucket sums in-place; also computes escore (folded in).
__global__ void k_s2(int* __restrict__ part,
                     const float* __restrict__ eemb, const float* __restrict__ att_src,
                     float* __restrict__ escore) {
    __shared__ int tmp[256];
    int tid = threadIdx.x;
    int v = (tid < NBUCK) ? part[tid] : 0;
    tmp[tid] = v;
    __syncthreads();
    for (int off = 1; off < 256; off <<= 1) {
        int t = (tid >= off) ? tmp[tid - off] : 0;
        __syncthreads();
        tmp[tid] += t;
        __syncthreads();
    }
    if (tid < NBUCK) part[tid] = tmp[tid] - v;
    if (tid >= 200 && tid < 200 + NLAYERS * ECLS * NHEADS) {
        int idx = tid - 200;
        int l = idx / (ECLS * NHEADS);
        int r = idx % (ECLS * NHEADS);
        int c = r >> 1;
        int h = r & 1;
        float s = 0.f;
        const float* ev = eemb + l * ECLS * HC + c * HC + h * 32;
        const float* av = att_src + l * HC + h * 32;
        for (int k = 0; k < 32; ++k) s += ev[k] * av[k];
        escore[idx] = s;
    }
}

__global__ void k_cscatter(const int* __restrict__ src, const int* __restrict__ dst,
                           const int* __restrict__ attr, const int* __restrict__ bbase,
                           const int* __restrict__ part, int* __restrict__ bkt) {
    __shared__ int cur[NBUCK];
    int tid = threadIdx.x, blk = blockIdx.x;
    for (int i = tid; i < NBUCK; i += 256) cur[i] = bbase[i * 256 + blk] + part[i];
    __syncthreads();
    int s0 = blk * EPB, e0 = s0 + EPB;
    for (int i = s0 + tid; i < e0; i += 256) {
        int d = dst[i];
        int b = d >> 9;
        int pos = atomicAdd(&cur[b], 1);
        bkt[pos] = src[i] | (attr[i] << 17) | ((d & 511) << 20);
    }
}

__global__ void k_fine(const int* __restrict__ part, const int* __restrict__ bkt,
                       int* __restrict__ packed, int* __restrict__ rowstart) {
    __shared__ int hist[512];
    __shared__ int cur[512];
    int b = blockIdx.x, tid = threadIdx.x;   // 512 threads
    int base = part[b];
    int bend = (b + 1 < NBUCK) ? part[b + 1] : N_EDGES;
    int nb = bend - base;
    hist[tid] = 0;
    __syncthreads();
    for (int i = tid; i < nb; i += 512)
        atomicAdd(&hist[(bkt[base + i] >> 20) & 0x1FF], 1);
    __syncthreads();
    int v = hist[tid];
    for (int off = 1; off < 512; off <<= 1) {
        int t = (tid >= off) ? hist[tid - off] : 0;
        __syncthreads();
        hist[tid] += t;
        __syncthreads();
    }
    int excl = hist[tid] - v;
    int node = (b << 9) + tid;
    if (node <= N_NODES) rowstart[node] = base + excl;
    cur[tid] = excl;
    __syncthreads();
    for (int i = tid; i < nb; i += 512) {
        int p = bkt[base + i];
        int r = atomicAdd(&cur[(p >> 20) & 0x1FF], 1);
        packed[base + r] = p;
    }
}

// ---------------- MFMA linear (layers 1..3) ----------------
__global__ void k_linmfma(const unsigned short* __restrict__ actB,
                          const float* __restrict__ Wl,       // [64][64] fp32
                          const float* __restrict__ asrc,     // [64]
                          const float* __restrict__ adst,     // [64]
                          unsigned short* __restrict__ hcurb,
                          float* __restrict__ ssrc, float* __restrict__ sdst) {
    __shared__ uint4 WB[512];
    __shared__ unsigned short Cb[4][1024];
    int tid = threadIdx.x;
    int lane = tid & 63;
    int w = tid >> 6;
    int q = lane >> 4;
    int c = lane & 15;

    for (int rid = tid; rid < 512; rid += 256) {
        int kk = rid >> 8;
        int t  = (rid >> 6) & 3;
        int ln = rid & 63;
        int qq = ln >> 4, cc = ln & 15;
        unsigned int u[4];
        #pragma unroll
        for (int jj = 0; jj < 4; ++jj) {
            float v0 = Wl[(kk * 32 + qq * 8 + jj * 2 + 0) * 64 + 16 * t + cc];
            float v1 = Wl[(kk * 32 + qq * 8 + jj * 2 + 1) * 64 + 16 * t + cc];
            u[jj] = (unsigned int)f2bf(v0) | ((unsigned int)f2bf(v1) << 16);
        }
        WB[rid] = make_uint4(u[0], u[1], u[2], u[3]);
    }
    __syncthreads();

    short8 bfr[2][4];
    #pragma unroll
    for (int kk = 0; kk < 2; ++kk)
        #pragma unroll
        for (int t = 0; t < 4; ++t) {
            F8 tmp; tmp.u = WB[(kk * 4 + t) * 64 + lane];
            bfr[kk][t] = tmp.s;
        }

    float as_[4], ad_[4];
    #pragma unroll
    for (int t = 0; t < 4; ++t) {
        as_[t] = asrc[16 * t + c];
        ad_[t] = adst[16 * t + c];
    }

    int wid = (blockIdx.x * 256 + tid) >> 6;
    int nwaves = gridDim.x * 4;

    for (int g = wid; g < NGRP; g += nwaves) {
        int base = g * 16;
        F8 a0, a1;
        a0.u = *(const uint4*)(actB + (size_t)(base + c) * HC + q * 8);
        a1.u = *(const uint4*)(actB + (size_t)(base + c) * HC + 32 + q * 8);

        floatx4 acc[4];
        #pragma unroll
        for (int t = 0; t < 4; ++t) {
            acc[t] = (floatx4){0.f, 0.f, 0.f, 0.f};
            acc[t] = __builtin_amdgcn_mfma_f32_16x16x32_bf16(a0.s, bfr[0][t], acc[t], 0, 0, 0);
            acc[t] = __builtin_amdgcn_mfma_f32_16x16x32_bf16(a1.s, bfr[1][t], acc[t], 0, 0, 0);
        }

        #pragma unroll
        for (int r = 0; r < 4; ++r) {
            float h0s = acc[0][r] * as_[0] + acc[1][r] * as_[1];
            float h1s = acc[2][r] * as_[2] + acc[3][r] * as_[3];
            float h0d = acc[0][r] * ad_[0] + acc[1][r] * ad_[1];
            float h1d = acc[2][r] * ad_[2] + acc[3][r] * ad_[3];
            #pragma unroll
            for (int off = 1; off < 16; off <<= 1) {
                h0s += __shfl_xor(h0s, off, 64);
                h1s += __shfl_xor(h1s, off, 64);
                h0d += __shfl_xor(h0d, off, 64);
                h1d += __shfl_xor(h1d, off, 64);
            }
            if (c == 0) {
                int node = base + q * 4 + r;
                *(float2*)(ssrc + node * 2) = make_float2(h0s, h1s);
                *(float2*)(sdst + node * 2) = make_float2(h0d, h1d);
            }
        }

        #pragma unroll
        for (int t = 0; t < 4; ++t)
            #pragma unroll
            for (int r = 0; r < 4; ++r)
                Cb[w][(q * 4 + r) * 64 + 16 * t + c] = f2bf(acc[t][r]);
        __builtin_amdgcn_wave_barrier();
        const uint4* cf = (const uint4*)&Cb[w][0];
        uint4* gout = (uint4*)(hcurb + (size_t)base * HC);
        gout[lane] = cf[lane];
        gout[64 + lane] = cf[64 + lane];
        __builtin_amdgcn_wave_barrier();
    }
}

// ---------------- fused edge pipeline ----------------
// Non-LAST: NW=2 (128-thread blocks) — 1-wave blocks hit the ~24 wg/CU slot
// cap at 75% occupancy; 2-wave blocks reach the full 32 waves/CU.
// LAST: 128-thread blocks; block b handles ONLY nodes 4b (user) and 4b+1
// (item) — nodes 4b+2/3 are never read by the decoder — then computes
// out[b] = dot(h[4b], h[4b+1]) in-block.
template <int NW, bool LAST>
__global__ void k_edge(const int* __restrict__ rowstart, const int* __restrict__ packed,
                       const float* __restrict__ ssrc, const float* __restrict__ sdst,
                       const float* __restrict__ escore_l,   // [5][2]
                       const unsigned short* __restrict__ hcurb, // [N][64] bf16
                       const float* __restrict__ eemb_l,     // [5][64]
                       const float* __restrict__ bias_l,     // [64]
                       unsigned short* __restrict__ actnext, float* __restrict__ out) {
    __shared__ float lbuf[NW][64];
    __shared__ float obuf[2][64];
    int w = threadIdx.x >> 6;
    int n = LAST ? (blockIdx.x * 4 + w) : (blockIdx.x * NW + w);
    int lane = threadIdx.x & 63;
    int sub = lane >> 3;
    int q   = lane & 7;
    int h   = q >> 2;

    int beg = rowstart[n];
    int end = rowstart[n + 1];
    float sd = sdst[n * 2 + h];

    float4 a0 = make_float4(0.f, 0.f, 0.f, 0.f);
    float4 a1 = make_float4(0.f, 0.f, 0.f, 0.f);
    float ssum = 0.f;
    for (int i = beg + sub; i < end; i += 8) {
        int p = packed[i];
        int s = p & 0x1FFFF;
        int a = (p >> 17) & 7;
        float lg = sd + ssrc[s * 2 + h] + escore_l[a * 2 + h];
        lg = lg >= 0.f ? lg : 0.2f * lg;
        float wt = __expf(lg);
        uint4 hv = *(const uint4*)(hcurb + (size_t)s * HC + q * 8);
        const float4* ep = (const float4*)(eemb_l + a * HC + q * 8);
        float4 e0 = ep[0], e1 = ep[1];
        a0.x += wt * (bf_lo(hv.x) + e0.x);
        a0.y += wt * (bf_hi(hv.x) + e0.y);
        a0.z += wt * (bf_lo(hv.y) + e0.z);
        a0.w += wt * (bf_hi(hv.y) + e0.w);
        a1.x += wt * (bf_lo(hv.z) + e1.x);
        a1.y += wt * (bf_hi(hv.z) + e1.y);
        a1.z += wt * (bf_lo(hv.w) + e1.z);
        a1.w += wt * (bf_hi(hv.w) + e1.w);
        ssum += wt;
    }
    for (int off = 8; off < 64; off <<= 1) {
        a0.x += __shfl_xor(a0.x, off, 64);
        a0.y += __shfl_xor(a0.y, off, 64);
        a0.z += __shfl_xor(a0.z, off, 64);
        a0.w += __shfl_xor(a0.w, off, 64);
        a1.x += __shfl_xor(a1.x, off, 64);
        a1.y += __shfl_xor(a1.y, off, 64);
        a1.z += __shfl_xor(a1.z, off, 64);
        a1.w += __shfl_xor(a1.w, off, 64);
        ssum  += __shfl_xor(ssum,  off, 64);
    }
    if (sub == 0) {
        ((float4*)&lbuf[w][q * 8])[0] = a0;
        ((float4*)&lbuf[w][q * 8])[1] = a1;
    }
    // ssum for head of CHANNEL `lane` (= lane>>5): lane 0 holds head0, lane 4 head1
    float ssum_h = __shfl(ssum, (lane >> 5) * 4, 64);
    float inv = 1.f / (ssum_h + 1e-16f);
    __builtin_amdgcn_wave_barrier();
    float v = lbuf[w][lane] * inv + bias_l[lane];
    float o = v > 0.f ? v : (__expf(v) - 1.f);
    if (!LAST) {
        actnext[(size_t)n * HC + lane] = f2bf(o);
    } else {
        obuf[w][lane] = o;                      // w=0: user 4b, w=1: item 4b+1
        __syncthreads();
        if (w == 0) {
            float p = obuf[0][lane] * obuf[1][lane];
            for (int off = 32; off > 0; off >>= 1) p += __shfl_down(p, off, 64);
            if (lane == 0) out[blockIdx.x] = p;
        }
    }
}

// ---------------- launch ----------------
extern "C" void kernel_launch(void* const* d_in, const int* in_sizes, int n_in,
                              void* d_out, int out_size, void* d_ws, size_t ws_size,
                              hipStream_t stream) {
    const float* x       = (const float*)d_in[0];   // [N,4]
    const float* W0      = (const float*)d_in[1];   // [4,64]
    const float* W13     = (const float*)d_in[2];   // [3,64,64]
    const float* eemb    = (const float*)d_in[3];   // [4,5,64]
    const float* att_src = (const float*)d_in[4];   // [4,2,32]
    const float* att_dst = (const float*)d_in[5];   // [4,2,32]
    const float* bias    = (const float*)d_in[6];   // [4,64]
    const int*   eidx    = (const int*)d_in[7];     // [2,E]
    const int*   eattr   = (const int*)d_in[8];     // [E]
    float* out = (float*)d_out;

    const int* src = eidx;
    const int* dst = eidx + N_EDGES;

    char* wsb = (char*)d_ws;
    size_t off = 0;
    auto alloc = [&](size_t bytes) { char* p = wsb + off; off += (bytes + 255) & ~(size_t)255; return p; };
    unsigned short* hcurb  = (unsigned short*)alloc((size_t)N_NODES * HC * 2);
    unsigned short* actB   = (unsigned short*)alloc((size_t)N_NODES * HC * 2);
    float*          ssrc   = (float*)alloc((size_t)N_NODES * 2 * 4);
    float*          sdst   = (float*)alloc((size_t)N_NODES * 2 * 4);
    float*          escore = (float*)alloc(NLAYERS * ECLS * NHEADS * 4);
    int*            bh     = (int*)alloc((size_t)NBUCK * 256 * 4);
    int*            bbase  = (int*)alloc((size_t)NBUCK * 256 * 4);
    int*            part   = (int*)alloc(256 * 4);
    int*            rowstart = (int*)alloc(((size_t)N_NODES + 1) * 4);
    int*            bkt    = (int*)alloc((size_t)N_EDGES * 4);
    int*            packed = (int*)alloc((size_t)N_EDGES * 4);

    // ---- CSR build P1 + layer-0 linear (merged) ----
    k_chist_lin0<<<NBLK + LIN0_BLOCKS, 256, 0, stream>>>(
        dst, bh, x, W0, att_src, att_dst, hcurb, ssrc, sdst);
    k_s1<<<NBUCK, 256, 0, stream>>>(bh, bbase, part);
    k_s2<<<1, 256, 0, stream>>>(part, eemb, att_src, escore);
    k_cscatter<<<NBLK, 256, 0, stream>>>(src, dst, eattr, bbase, part, bkt);
    k_fine<<<NBUCK, 512, 0, stream>>>(part, bkt, packed, rowstart);

    for (int l = 0; l < NLAYERS; ++l) {
        if (l > 0) {
            k_linmfma<<<512, 256, 0, stream>>>(
                actB, W13 + (size_t)(l - 1) * HC * HC,
                att_src + l * HC, att_dst + l * HC, hcurb, ssrc, sdst);
        }
        const float* esl = escore + l * ECLS * NHEADS;
        const float* el  = eemb + (size_t)l * ECLS * HC;
        const float* bl  = bias + l * HC;
        if (l < NLAYERS - 1)
            k_edge<2, false><<<N_NODES / 2, 128, 0, stream>>>(
                rowstart, packed, ssrc, sdst, esl, hcurb, el, bl, actB, nullptr);
        else
            k_edge<2, true><<<N_NODES / 4, 128, 0, stream>>>(
                rowstart, packed, ssrc, sdst, esl, hcurb, el, bl, nullptr, out);
    }
}

// Round 17
// 333.450 us; speedup vs baseline: 1.0383x; 1.0383x over previous
//
#include <hip/hip_runtime.h>
#include <hip/hip_bf16.h>
#include <math.h>

#define N_NODES 100000
#define N_EDGES 1600000
#define HC 64          // H*C
#define NHEADS 2
#define NLAYERS 4
#define ECLS 5
#define NBUCK 196              // ceil(N / 512); bucket = dst >> 9
#define NBLK 512               // coarse pass blocks
#define EPB (N_EDGES / NBLK)   // 3125 edges per coarse block (exact)
#define NGRP (N_NODES / 16)    // 6250 16-node groups (exact)
#define LIN0_BLOCKS 1024
#define FCAP 12288             // k_fine LDS staging capacity (avg bucket ~8163)

typedef __attribute__((ext_vector_type(8))) short short8;
typedef __attribute__((ext_vector_type(4))) float floatx4;
union F8 { uint4 u; short8 s; };

// bf16 (stored as ushort) -> f32
__device__ inline float bf_lo(unsigned int u) { return __uint_as_float(u << 16); }
__device__ inline float bf_hi(unsigned int u) { return __uint_as_float(u & 0xffff0000u); }
// f32 -> bf16 bits, round-to-nearest-even
__device__ inline unsigned short f2bf(float f) {
    unsigned int u = __float_as_uint(f);
    u += 0x7FFFu + ((u >> 16) & 1u);
    return (unsigned short)(u >> 16);
}

// ---------------- CSR P1 + layer-0 linear (merged: independent work) -------
// Blocks [0,NBLK): per-(bucket,block) histogram. Blocks [NBLK,+LIN0): lin0.
__global__ void k_chist_lin0(const int* __restrict__ dst, int* __restrict__ bh,
                             const float* __restrict__ in,
                             const float* __restrict__ W,        // [4][64]
                             const float* __restrict__ asrc, const float* __restrict__ adst,
                             unsigned short* __restrict__ hcurb,
                             float* __restrict__ ssrc, float* __restrict__ sdst) {
    int tid = threadIdx.x;
    if (blockIdx.x < NBLK) {
        __shared__ int lh[NBUCK];
        int blk = blockIdx.x;
        for (int i = tid; i < NBUCK; i += 256) lh[i] = 0;
        __syncthreads();
        int s = blk * EPB;
        for (int i = tid; i < EPB; i += 256) atomicAdd(&lh[dst[s + i] >> 9], 1);
        __syncthreads();
        for (int i = tid; i < NBUCK; i += 256) bh[i * NBLK + blk] = lh[i];
        return;
    }
    int j = tid & 63;
    int wid = ((blockIdx.x - NBLK) * 256 + tid) >> 6;
    int nwaves = LIN0_BLOCKS * 4;

    float w0 = W[0 * HC + j], w1 = W[1 * HC + j], w2 = W[2 * HC + j], w3 = W[3 * HC + j];
    int head = j >> 5;
    int c = j & 31;
    float as = asrc[head * 32 + c];
    float ad = adst[head * 32 + c];

    for (int n = wid; n < N_NODES; n += nwaves) {
        int nu = __builtin_amdgcn_readfirstlane(n);
        float4 r = *(const float4*)(in + (size_t)nu * 4);
        float acc = r.x * w0 + r.y * w1 + r.z * w2 + r.w * w3;
        hcurb[(size_t)nu * HC + j] = f2bf(acc);
        float ps = acc * as;
        float pd = acc * ad;
        for (int off = 16; off > 0; off >>= 1) {
            ps += __shfl_down(ps, off, 32);
            pd += __shfl_down(pd, off, 32);
        }
        if (c == 0) {
            ssrc[nu * 2 + head] = ps;
            sdst[nu * 2 + head] = pd;
        }
    }
}

// P2a: per-bucket exclusive scan of the NBLK per-block counts. 512 threads.
__global__ void k_s1(const int* __restrict__ bh, int* __restrict__ bbase,
                     int* __restrict__ part) {
    __shared__ int tmp[NBLK];
    int tid = threadIdx.x;
    int i = blockIdx.x * NBLK + tid;
    int v = bh[i];
    tmp[tid] = v;
    __syncthreads();
    for (int off = 1; off < NBLK; off <<= 1) {
        int t = (tid >= off) ? tmp[tid - off] : 0;
        __syncthreads();
        tmp[tid] += t;
        __syncthreads();
    }
    bbase[i] = tmp[tid] - v;
    if (tid == NBLK - 1) part[blockIdx.x] = tmp[NBLK - 1];
}

// P2b: exclusive scan of bucket sums in-place; also computes escore.
__global__ void k_s2(int* __restrict__ part,
                     const float* __restrict__ eemb, const float* __restrict__ att_src,
                     float* __restrict__ escore) {
    __shared__ int tmp[256];
    int tid = threadIdx.x;
    int v = (tid < NBUCK) ? part[tid] : 0;
    tmp[tid] = v;
    __syncthreads();
    for (int off = 1; off < 256; off <<= 1) {
        int t = (tid >= off) ? tmp[tid - off] : 0;
        __syncthreads();
        tmp[tid] += t;
        __syncthreads();
    }
    if (tid < NBUCK) part[tid] = tmp[tid] - v;
    if (tid >= 200 && tid < 200 + NLAYERS * ECLS * NHEADS) {
        int idx = tid - 200;
        int l = idx / (ECLS * NHEADS);
        int r = idx % (ECLS * NHEADS);
        int c = r >> 1;
        int h = r & 1;
        float s = 0.f;
        const float* ev = eemb + l * ECLS * HC + c * HC + h * 32;
        const float* av = att_src + l * HC + h * 32;
        for (int k = 0; k < 32; ++k) s += ev[k] * av[k];
        escore[idx] = s;
    }
}

// P3: coarse scatter, LDS-STAGED. Block sorts its EPB edges into LDS by
// bucket, then flushes contiguous runs -> coalesced global writes (no
// random 4B write-allocate).
__global__ void k_cscatter(const int* __restrict__ src, const int* __restrict__ dst,
                           const int* __restrict__ attr, const int* __restrict__ bbase,
                           const int* __restrict__ part, int* __restrict__ bkt) {
    __shared__ int tmp[256];
    __shared__ int cur[NBUCK];
    __shared__ int gadj[NBUCK];
    __shared__ int stage[EPB];            // 12.5 KB
    __shared__ unsigned char stb[EPB];    // 3.1 KB
    int tid = threadIdx.x, blk = blockIdx.x;
    for (int i = tid; i < NBUCK; i += 256) cur[i] = 0;
    __syncthreads();
    int s0 = blk * EPB;
    for (int i = tid; i < EPB; i += 256) atomicAdd(&cur[dst[s0 + i] >> 9], 1);
    __syncthreads();
    int v = (tid < NBUCK) ? cur[tid] : 0;
    tmp[tid] = v;
    __syncthreads();
    for (int off = 1; off < 256; off <<= 1) {
        int t = (tid >= off) ? tmp[tid - off] : 0;
        __syncthreads();
        tmp[tid] += t;
        __syncthreads();
    }
    int ex = tmp[tid] - v;
    if (tid < NBUCK) {
        cur[tid] = ex;                                    // local cursor
        gadj[tid] = bbase[tid * NBLK + blk] + part[tid] - ex;  // global - local
    }
    __syncthreads();
    for (int i = tid; i < EPB; i += 256) {
        int e = s0 + i;
        int d = dst[e];
        int b = d >> 9;
        int pos = atomicAdd(&cur[b], 1);
        stage[pos] = src[e] | (attr[e] << 17) | ((d & 511) << 20);
        stb[pos] = (unsigned char)b;
    }
    __syncthreads();
    // flush: consecutive i within a bucket run -> consecutive global addrs
    for (int i = tid; i < EPB; i += 256)
        bkt[gadj[stb[i]] + i] = stage[i];
}

// P4: fine sort within each bucket, LDS-STAGED (fallback to global scatter
// if a bucket exceeds FCAP). Emits final packed + rowstart.
__global__ void k_fine(const int* __restrict__ part, const int* __restrict__ bkt,
                       int* __restrict__ packed, int* __restrict__ rowstart) {
    __shared__ int hist[512];
    __shared__ int cur[512];
    __shared__ int stage[FCAP];           // 48 KB
    int b = blockIdx.x, tid = threadIdx.x;   // 512 threads
    int base = part[b];
    int bend = (b + 1 < NBUCK) ? part[b + 1] : N_EDGES;
    int nb = bend - base;
    hist[tid] = 0;
    __syncthreads();
    for (int i = tid; i < nb; i += 512)
        atomicAdd(&hist[(bkt[base + i] >> 20) & 0x1FF], 1);
    __syncthreads();
    int v = hist[tid];
    for (int off = 1; off < 512; off <<= 1) {
        int t = (tid >= off) ? hist[tid - off] : 0;
        __syncthreads();
        hist[tid] += t;
        __syncthreads();
    }
    int excl = hist[tid] - v;
    int node = (b << 9) + tid;
    if (node <= N_NODES) rowstart[node] = base + excl;
    cur[tid] = excl;
    __syncthreads();
    if (nb <= FCAP) {
        for (int i = tid; i < nb; i += 512) {
            int p = bkt[base + i];
            int r = atomicAdd(&cur[(p >> 20) & 0x1FF], 1);
            stage[r] = p;
        }
        __syncthreads();
        for (int i = tid; i < nb; i += 512) packed[base + i] = stage[i];
    } else {
        for (int i = tid; i < nb; i += 512) {
            int p = bkt[base + i];
            int r = atomicAdd(&cur[(p >> 20) & 0x1FF], 1);
            packed[base + r] = p;
        }
    }
}

// ---------------- MFMA linear (layers 1..3) ----------------
__global__ void k_linmfma(const unsigned short* __restrict__ actB,
                          const float* __restrict__ Wl,       // [64][64] fp32
                          const float* __restrict__ asrc,     // [64]
                          const float* __restrict__ adst,     // [64]
                          unsigned short* __restrict__ hcurb,
                          float* __restrict__ ssrc, float* __restrict__ sdst) {
    __shared__ uint4 WB[512];
    __shared__ unsigned short Cb[4][1024];
    int tid = threadIdx.x;
    int lane = tid & 63;
    int w = tid >> 6;
    int q = lane >> 4;
    int c = lane & 15;

    for (int rid = tid; rid < 512; rid += 256) {
        int kk = rid >> 8;
        int t  = (rid >> 6) & 3;
        int ln = rid & 63;
        int qq = ln >> 4, cc = ln & 15;
        unsigned int u[4];
        #pragma unroll
        for (int jj = 0; jj < 4; ++jj) {
            float v0 = Wl[(kk * 32 + qq * 8 + jj * 2 + 0) * 64 + 16 * t + cc];
            float v1 = Wl[(kk * 32 + qq * 8 + jj * 2 + 1) * 64 + 16 * t + cc];
            u[jj] = (unsigned int)f2bf(v0) | ((unsigned int)f2bf(v1) << 16);
        }
        WB[rid] = make_uint4(u[0], u[1], u[2], u[3]);
    }
    __syncthreads();

    short8 bfr[2][4];
    #pragma unroll
    for (int kk = 0; kk < 2; ++kk)
        #pragma unroll
        for (int t = 0; t < 4; ++t) {
            F8 tmp; tmp.u = WB[(kk * 4 + t) * 64 + lane];
            bfr[kk][t] = tmp.s;
        }

    float as_[4], ad_[4];
    #pragma unroll
    for (int t = 0; t < 4; ++t) {
        as_[t] = asrc[16 * t + c];
        ad_[t] = adst[16 * t + c];
    }

    int wid = (blockIdx.x * 256 + tid) >> 6;
    int nwaves = gridDim.x * 4;

    for (int g = wid; g < NGRP; g += nwaves) {
        int base = g * 16;
        F8 a0, a1;
        a0.u = *(const uint4*)(actB + (size_t)(base + c) * HC + q * 8);
        a1.u = *(const uint4*)(actB + (size_t)(base + c) * HC + 32 + q * 8);

        floatx4 acc[4];
        #pragma unroll
        for (int t = 0; t < 4; ++t) {
            acc[t] = (floatx4){0.f, 0.f, 0.f, 0.f};
            acc[t] = __builtin_amdgcn_mfma_f32_16x16x32_bf16(a0.s, bfr[0][t], acc[t], 0, 0, 0);
            acc[t] = __builtin_amdgcn_mfma_f32_16x16x32_bf16(a1.s, bfr[1][t], acc[t], 0, 0, 0);
        }

        #pragma unroll
        for (int r = 0; r < 4; ++r) {
            float h0s = acc[0][r] * as_[0] + acc[1][r] * as_[1];
            float h1s = acc[2][r] * as_[2] + acc[3][r] * as_[3];
            float h0d = acc[0][r] * ad_[0] + acc[1][r] * ad_[1];
            float h1d = acc[2][r] * ad_[2] + acc[3][r] * ad_[3];
            #pragma unroll
            for (int off = 1; off < 16; off <<= 1) {
                h0s += __shfl_xor(h0s, off, 64);
                h1s += __shfl_xor(h1s, off, 64);
                h0d += __shfl_xor(h0d, off, 64);
                h1d += __shfl_xor(h1d, off, 64);
            }
            if (c == 0) {
                int node = base + q * 4 + r;
                *(float2*)(ssrc + node * 2) = make_float2(h0s, h1s);
                *(float2*)(sdst + node * 2) = make_float2(h0d, h1d);
            }
        }

        #pragma unroll
        for (int t = 0; t < 4; ++t)
            #pragma unroll
            for (int r = 0; r < 4; ++r)
                Cb[w][(q * 4 + r) * 64 + 16 * t + c] = f2bf(acc[t][r]);
        __builtin_amdgcn_wave_barrier();
        const uint4* cf = (const uint4*)&Cb[w][0];
        uint4* gout = (uint4*)(hcurb + (size_t)base * HC);
        gout[lane] = cf[lane];
        gout[64 + lane] = cf[64 + lane];
        __builtin_amdgcn_wave_barrier();
    }
}

// ---------------- fused edge pipeline ----------------
// Non-LAST: NW=1 (64-thread blocks) — measured best (75% occ, 52.5 µs).
// LAST: 128-thread blocks; block b handles ONLY nodes 4b (user) and 4b+1
// (item), then computes out[b] = dot(h[4b], h[4b+1]) in-block.
template <int NW, bool LAST>
__global__ void k_edge(const int* __restrict__ rowstart, const int* __restrict__ packed,
                       const float* __restrict__ ssrc, const float* __restrict__ sdst,
                       const float* __restrict__ escore_l,   // [5][2]
                       const unsigned short* __restrict__ hcurb, // [N][64] bf16
                       const float* __restrict__ eemb_l,     // [5][64]
                       const float* __restrict__ bias_l,     // [64]
                       unsigned short* __restrict__ actnext, float* __restrict__ out) {
    __shared__ float lbuf[NW][64];
    __shared__ float obuf[2][64];
    int w = threadIdx.x >> 6;
    int n = LAST ? (blockIdx.x * 4 + w) : (blockIdx.x * NW + w);
    int lane = threadIdx.x & 63;
    int sub = lane >> 3;
    int q   = lane & 7;
    int h   = q >> 2;

    int beg = rowstart[n];
    int end = rowstart[n + 1];
    float sd = sdst[n * 2 + h];

    float4 a0 = make_float4(0.f, 0.f, 0.f, 0.f);
    float4 a1 = make_float4(0.f, 0.f, 0.f, 0.f);
    float ssum = 0.f;
    for (int i = beg + sub; i < end; i += 8) {
        int p = packed[i];
        int s = p & 0x1FFFF;
        int a = (p >> 17) & 7;
        float lg = sd + ssrc[s * 2 + h] + escore_l[a * 2 + h];
        lg = lg >= 0.f ? lg : 0.2f * lg;
        float wt = __expf(lg);
        uint4 hv = *(const uint4*)(hcurb + (size_t)s * HC + q * 8);
        const float4* ep = (const float4*)(eemb_l + a * HC + q * 8);
        float4 e0 = ep[0], e1 = ep[1];
        a0.x += wt * (bf_lo(hv.x) + e0.x);
        a0.y += wt * (bf_hi(hv.x) + e0.y);
        a0.z += wt * (bf_lo(hv.y) + e0.z);
        a0.w += wt * (bf_hi(hv.y) + e0.w);
        a1.x += wt * (bf_lo(hv.z) + e1.x);
        a1.y += wt * (bf_hi(hv.z) + e1.y);
        a1.z += wt * (bf_lo(hv.w) + e1.z);
        a1.w += wt * (bf_hi(hv.w) + e1.w);
        ssum += wt;
    }
    for (int off = 8; off < 64; off <<= 1) {
        a0.x += __shfl_xor(a0.x, off, 64);
        a0.y += __shfl_xor(a0.y, off, 64);
        a0.z += __shfl_xor(a0.z, off, 64);
        a0.w += __shfl_xor(a0.w, off, 64);
        a1.x += __shfl_xor(a1.x, off, 64);
        a1.y += __shfl_xor(a1.y, off, 64);
        a1.z += __shfl_xor(a1.z, off, 64);
        a1.w += __shfl_xor(a1.w, off, 64);
        ssum  += __shfl_xor(ssum,  off, 64);
    }
    if (sub == 0) {
        ((float4*)&lbuf[w][q * 8])[0] = a0;
        ((float4*)&lbuf[w][q * 8])[1] = a1;
    }
    // ssum for head of CHANNEL `lane` (= lane>>5): lane 0 holds head0, lane 4 head1
    float ssum_h = __shfl(ssum, (lane >> 5) * 4, 64);
    float inv = 1.f / (ssum_h + 1e-16f);
    __builtin_amdgcn_wave_barrier();
    float v = lbuf[w][lane] * inv + bias_l[lane];
    float o = v > 0.f ? v : (__expf(v) - 1.f);
    if (!LAST) {
        actnext[(size_t)n * HC + lane] = f2bf(o);
    } else {
        obuf[w][lane] = o;                      // w=0: user 4b, w=1: item 4b+1
        __syncthreads();
        if (w == 0) {
            float p = obuf[0][lane] * obuf[1][lane];
            for (int off = 32; off > 0; off >>= 1) p += __shfl_down(p, off, 64);
            if (lane == 0) out[blockIdx.x] = p;
        }
    }
}

// ---------------- launch ----------------
extern "C" void kernel_launch(void* const* d_in, const int* in_sizes, int n_in,
                              void* d_out, int out_size, void* d_ws, size_t ws_size,
                              hipStream_t stream) {
    const float* x       = (const float*)d_in[0];   // [N,4]
    const float* W0      = (const float*)d_in[1];   // [4,64]
    const float* W13     = (const float*)d_in[2];   // [3,64,64]
    const float* eemb    = (const float*)d_in[3];   // [4,5,64]
    const float* att_src = (const float*)d_in[4];   // [4,2,32]
    const float* att_dst = (const float*)d_in[5];   // [4,2,32]
    const float* bias    = (const float*)d_in[6];   // [4,64]
    const int*   eidx    = (const int*)d_in[7];     // [2,E]
    const int*   eattr   = (const int*)d_in[8];     // [E]
    float* out = (float*)d_out;

    const int* src = eidx;
    const int* dst = eidx + N_EDGES;

    char* wsb = (char*)d_ws;
    size_t off = 0;
    auto alloc = [&](size_t bytes) { char* p = wsb + off; off += (bytes + 255) & ~(size_t)255; return p; };
    unsigned short* hcurb  = (unsigned short*)alloc((size_t)N_NODES * HC * 2);
    unsigned short* actB   = (unsigned short*)alloc((size_t)N_NODES * HC * 2);
    float*          ssrc   = (float*)alloc((size_t)N_NODES * 2 * 4);
    float*          sdst   = (float*)alloc((size_t)N_NODES * 2 * 4);
    float*          escore = (float*)alloc(NLAYERS * ECLS * NHEADS * 4);
    int*            bh     = (int*)alloc((size_t)NBUCK * NBLK * 4);
    int*            bbase  = (int*)alloc((size_t)NBUCK * NBLK * 4);
    int*            part   = (int*)alloc(256 * 4);
    int*            rowstart = (int*)alloc(((size_t)N_NODES + 1) * 4);
    int*            bkt    = (int*)alloc((size_t)N_EDGES * 4);
    int*            packed = (int*)alloc((size_t)N_EDGES * 4);

    // ---- CSR build P1 + layer-0 linear (merged) ----
    k_chist_lin0<<<NBLK + LIN0_BLOCKS, 256, 0, stream>>>(
        dst, bh, x, W0, att_src, att_dst, hcurb, ssrc, sdst);
    k_s1<<<NBUCK, NBLK, 0, stream>>>(bh, bbase, part);
    k_s2<<<1, 256, 0, stream>>>(part, eemb, att_src, escore);
    k_cscatter<<<NBLK, 256, 0, stream>>>(src, dst, eattr, bbase, part, bkt);
    k_fine<<<NBUCK, 512, 0, stream>>>(part, bkt, packed, rowstart);

    for (int l = 0; l < NLAYERS; ++l) {
        if (l > 0) {
            k_linmfma<<<512, 256, 0, stream>>>(
                actB, W13 + (size_t)(l - 1) * HC * HC,
                att_src + l * HC, att_dst + l * HC, hcurb, ssrc, sdst);
        }
        const float* esl = escore + l * ECLS * NHEADS;
        const float* el  = eemb + (size_t)l * ECLS * HC;
        const float* bl  = bias + l * HC;
        if (l < NLAYERS - 1)
            k_edge<1, false><<<N_NODES, 64, 0, stream>>>(
                rowstart, packed, ssrc, sdst, esl, hcurb, el, bl, actB, nullptr);
        else
            k_edge<2, true><<<N_NODES / 4, 128, 0, stream>>>(
                rowstart, packed, ssrc, sdst, esl, hcurb, el, bl, nullptr, out);
    }
}

// Round 18
// 320.458 us; speedup vs baseline: 1.0804x; 1.0405x over previous
//
#include <hip/hip_runtime.h>
#include <hip/hip_bf16.h>
#include <math.h>

#define N_NODES 100000
#define N_EDGES 1600000
#define HC 64          // H*C
#define NHEADS 2
#define NLAYERS 4
#define ECLS 5
#define NBUCK 196              // ceil(N / 512); bucket = dst >> 9
#define NBLK 512               // coarse pass blocks
#define EPB (N_EDGES / NBLK)   // 3125 edges per coarse block (exact)
#define NGRP (N_NODES / 16)    // 6250 16-node groups (exact)
#define LIN0_BLOCKS 1024
#define FCAP 12288             // k_fine LDS staging capacity (avg bucket ~8163)

typedef __attribute__((ext_vector_type(8))) short short8;
typedef __attribute__((ext_vector_type(4))) float floatx4;
union F8 { uint4 u; short8 s; };

// bf16 (stored as ushort) -> f32
__device__ inline float bf_lo(unsigned int u) { return __uint_as_float(u << 16); }
__device__ inline float bf_hi(unsigned int u) { return __uint_as_float(u & 0xffff0000u); }
// f32 -> bf16 bits, round-to-nearest-even
__device__ inline unsigned short f2bf(float f) {
    unsigned int u = __float_as_uint(f);
    u += 0x7FFFu + ((u >> 16) & 1u);
    return (unsigned short)(u >> 16);
}

// ---------------- CSR P1 + layer-0 linear (merged: independent work) -------
__global__ void k_chist_lin0(const int* __restrict__ dst, int* __restrict__ bh,
                             const float* __restrict__ in,
                             const float* __restrict__ W,        // [4][64]
                             const float* __restrict__ asrc, const float* __restrict__ adst,
                             unsigned short* __restrict__ hcurb,
                             float* __restrict__ ssrc, float* __restrict__ sdst) {
    int tid = threadIdx.x;
    if (blockIdx.x < NBLK) {
        __shared__ int lh[NBUCK];
        int blk = blockIdx.x;
        for (int i = tid; i < NBUCK; i += 256) lh[i] = 0;
        __syncthreads();
        int s = blk * EPB;
        for (int i = tid; i < EPB; i += 256) atomicAdd(&lh[dst[s + i] >> 9], 1);
        __syncthreads();
        for (int i = tid; i < NBUCK; i += 256) bh[i * NBLK + blk] = lh[i];
        return;
    }
    int j = tid & 63;
    int wid = ((blockIdx.x - NBLK) * 256 + tid) >> 6;
    int nwaves = LIN0_BLOCKS * 4;

    float w0 = W[0 * HC + j], w1 = W[1 * HC + j], w2 = W[2 * HC + j], w3 = W[3 * HC + j];
    int head = j >> 5;
    int c = j & 31;
    float as = asrc[head * 32 + c];
    float ad = adst[head * 32 + c];

    for (int n = wid; n < N_NODES; n += nwaves) {
        int nu = __builtin_amdgcn_readfirstlane(n);
        float4 r = *(const float4*)(in + (size_t)nu * 4);
        float acc = r.x * w0 + r.y * w1 + r.z * w2 + r.w * w3;
        hcurb[(size_t)nu * HC + j] = f2bf(acc);
        float ps = acc * as;
        float pd = acc * ad;
        for (int off = 16; off > 0; off >>= 1) {
            ps += __shfl_down(ps, off, 32);
            pd += __shfl_down(pd, off, 32);
        }
        if (c == 0) {
            ssrc[nu * 2 + head] = ps;
            sdst[nu * 2 + head] = pd;
        }
    }
}

// P2a: per-bucket exclusive scan of the NBLK per-block counts. 512 threads.
__global__ void k_s1(const int* __restrict__ bh, int* __restrict__ bbase,
                     int* __restrict__ part) {
    __shared__ int tmp[NBLK];
    int tid = threadIdx.x;
    int i = blockIdx.x * NBLK + tid;
    int v = bh[i];
    tmp[tid] = v;
    __syncthreads();
    for (int off = 1; off < NBLK; off <<= 1) {
        int t = (tid >= off) ? tmp[tid - off] : 0;
        __syncthreads();
        tmp[tid] += t;
        __syncthreads();
    }
    bbase[i] = tmp[tid] - v;
    if (tid == NBLK - 1) part[blockIdx.x] = tmp[NBLK - 1];
}

// P2b: exclusive scan of bucket sums in-place; also computes escore.
__global__ void k_s2(int* __restrict__ part,
                     const float* __restrict__ eemb, const float* __restrict__ att_src,
                     float* __restrict__ escore) {
    __shared__ int tmp[256];
    int tid = threadIdx.x;
    int v = (tid < NBUCK) ? part[tid] : 0;
    tmp[tid] = v;
    __syncthreads();
    for (int off = 1; off < 256; off <<= 1) {
        int t = (tid >= off) ? tmp[tid - off] : 0;
        __syncthreads();
        tmp[tid] += t;
        __syncthreads();
    }
    if (tid < NBUCK) part[tid] = tmp[tid] - v;
    if (tid >= 200 && tid < 200 + NLAYERS * ECLS * NHEADS) {
        int idx = tid - 200;
        int l = idx / (ECLS * NHEADS);
        int r = idx % (ECLS * NHEADS);
        int c = r >> 1;
        int h = r & 1;
        float s = 0.f;
        const float* ev = eemb + l * ECLS * HC + c * HC + h * 32;
        const float* av = att_src + l * HC + h * 32;
        for (int k = 0; k < 32; ++k) s += ev[k] * av[k];
        escore[idx] = s;
    }
}

// P3: coarse scatter, LDS-STAGED -> coalesced global writes.
__global__ void k_cscatter(const int* __restrict__ src, const int* __restrict__ dst,
                           const int* __restrict__ attr, const int* __restrict__ bbase,
                           const int* __restrict__ part, int* __restrict__ bkt) {
    __shared__ int tmp[256];
    __shared__ int cur[NBUCK];
    __shared__ int gadj[NBUCK];
    __shared__ int stage[EPB];            // 12.5 KB
    __shared__ unsigned char stb[EPB];    // 3.1 KB
    int tid = threadIdx.x, blk = blockIdx.x;
    for (int i = tid; i < NBUCK; i += 256) cur[i] = 0;
    __syncthreads();
    int s0 = blk * EPB;
    for (int i = tid; i < EPB; i += 256) atomicAdd(&cur[dst[s0 + i] >> 9], 1);
    __syncthreads();
    int v = (tid < NBUCK) ? cur[tid] : 0;
    tmp[tid] = v;
    __syncthreads();
    for (int off = 1; off < 256; off <<= 1) {
        int t = (tid >= off) ? tmp[tid - off] : 0;
        __syncthreads();
        tmp[tid] += t;
        __syncthreads();
    }
    int ex = tmp[tid] - v;
    if (tid < NBUCK) {
        cur[tid] = ex;                                    // local cursor
        gadj[tid] = bbase[tid * NBLK + blk] + part[tid] - ex;  // global - local
    }
    __syncthreads();
    for (int i = tid; i < EPB; i += 256) {
        int e = s0 + i;
        int d = dst[e];
        int b = d >> 9;
        int pos = atomicAdd(&cur[b], 1);
        stage[pos] = src[e] | (attr[e] << 17) | ((d & 511) << 20);
        stb[pos] = (unsigned char)b;
    }
    __syncthreads();
    for (int i = tid; i < EPB; i += 256)
        bkt[gadj[stb[i]] + i] = stage[i];
}

// P4: fine sort within each bucket, LDS-STAGED (fallback if > FCAP).
__global__ void k_fine(const int* __restrict__ part, const int* __restrict__ bkt,
                       int* __restrict__ packed, int* __restrict__ rowstart) {
    __shared__ int hist[512];
    __shared__ int cur[512];
    __shared__ int stage[FCAP];           // 48 KB
    int b = blockIdx.x, tid = threadIdx.x;   // 512 threads
    int base = part[b];
    int bend = (b + 1 < NBUCK) ? part[b + 1] : N_EDGES;
    int nb = bend - base;
    hist[tid] = 0;
    __syncthreads();
    for (int i = tid; i < nb; i += 512)
        atomicAdd(&hist[(bkt[base + i] >> 20) & 0x1FF], 1);
    __syncthreads();
    int v = hist[tid];
    for (int off = 1; off < 512; off <<= 1) {
        int t = (tid >= off) ? hist[tid - off] : 0;
        __syncthreads();
        hist[tid] += t;
        __syncthreads();
    }
    int excl = hist[tid] - v;
    int node = (b << 9) + tid;
    if (node <= N_NODES) rowstart[node] = base + excl;
    cur[tid] = excl;
    __syncthreads();
    if (nb <= FCAP) {
        for (int i = tid; i < nb; i += 512) {
            int p = bkt[base + i];
            int r = atomicAdd(&cur[(p >> 20) & 0x1FF], 1);
            stage[r] = p;
        }
        __syncthreads();
        for (int i = tid; i < nb; i += 512) packed[base + i] = stage[i];
    } else {
        for (int i = tid; i < nb; i += 512) {
            int p = bkt[base + i];
            int r = atomicAdd(&cur[(p >> 20) & 0x1FF], 1);
            packed[base + r] = p;
        }
    }
}

// ---------------- MFMA linear (layers 1..3) ----------------
__global__ void k_linmfma(const unsigned short* __restrict__ actB,
                          const float* __restrict__ Wl,       // [64][64] fp32
                          const float* __restrict__ asrc,     // [64]
                          const float* __restrict__ adst,     // [64]
                          unsigned short* __restrict__ hcurb,
                          float* __restrict__ ssrc, float* __restrict__ sdst) {
    __shared__ uint4 WB[512];
    __shared__ unsigned short Cb[4][1024];
    int tid = threadIdx.x;
    int lane = tid & 63;
    int w = tid >> 6;
    int q = lane >> 4;
    int c = lane & 15;

    for (int rid = tid; rid < 512; rid += 256) {
        int kk = rid >> 8;
        int t  = (rid >> 6) & 3;
        int ln = rid & 63;
        int qq = ln >> 4, cc = ln & 15;
        unsigned int u[4];
        #pragma unroll
        for (int jj = 0; jj < 4; ++jj) {
            float v0 = Wl[(kk * 32 + qq * 8 + jj * 2 + 0) * 64 + 16 * t + cc];
            float v1 = Wl[(kk * 32 + qq * 8 + jj * 2 + 1) * 64 + 16 * t + cc];
            u[jj] = (unsigned int)f2bf(v0) | ((unsigned int)f2bf(v1) << 16);
        }
        WB[rid] = make_uint4(u[0], u[1], u[2], u[3]);
    }
    __syncthreads();

    short8 bfr[2][4];
    #pragma unroll
    for (int kk = 0; kk < 2; ++kk)
        #pragma unroll
        for (int t = 0; t < 4; ++t) {
            F8 tmp; tmp.u = WB[(kk * 4 + t) * 64 + lane];
            bfr[kk][t] = tmp.s;
        }

    float as_[4], ad_[4];
    #pragma unroll
    for (int t = 0; t < 4; ++t) {
        as_[t] = asrc[16 * t + c];
        ad_[t] = adst[16 * t + c];
    }

    int wid = (blockIdx.x * 256 + tid) >> 6;
    int nwaves = gridDim.x * 4;

    for (int g = wid; g < NGRP; g += nwaves) {
        int base = g * 16;
        F8 a0, a1;
        a0.u = *(const uint4*)(actB + (size_t)(base + c) * HC + q * 8);
        a1.u = *(const uint4*)(actB + (size_t)(base + c) * HC + 32 + q * 8);

        floatx4 acc[4];
        #pragma unroll
        for (int t = 0; t < 4; ++t) {
            acc[t] = (floatx4){0.f, 0.f, 0.f, 0.f};
            acc[t] = __builtin_amdgcn_mfma_f32_16x16x32_bf16(a0.s, bfr[0][t], acc[t], 0, 0, 0);
            acc[t] = __builtin_amdgcn_mfma_f32_16x16x32_bf16(a1.s, bfr[1][t], acc[t], 0, 0, 0);
        }

        #pragma unroll
        for (int r = 0; r < 4; ++r) {
            float h0s = acc[0][r] * as_[0] + acc[1][r] * as_[1];
            float h1s = acc[2][r] * as_[2] + acc[3][r] * as_[3];
            float h0d = acc[0][r] * ad_[0] + acc[1][r] * ad_[1];
            float h1d = acc[2][r] * ad_[2] + acc[3][r] * ad_[3];
            #pragma unroll
            for (int off = 1; off < 16; off <<= 1) {
                h0s += __shfl_xor(h0s, off, 64);
                h1s += __shfl_xor(h1s, off, 64);
                h0d += __shfl_xor(h0d, off, 64);
                h1d += __shfl_xor(h1d, off, 64);
            }
            if (c == 0) {
                int node = base + q * 4 + r;
                *(float2*)(ssrc + node * 2) = make_float2(h0s, h1s);
                *(float2*)(sdst + node * 2) = make_float2(h0d, h1d);
            }
        }

        #pragma unroll
        for (int t = 0; t < 4; ++t)
            #pragma unroll
            for (int r = 0; r < 4; ++r)
                Cb[w][(q * 4 + r) * 64 + 16 * t + c] = f2bf(acc[t][r]);
        __builtin_amdgcn_wave_barrier();
        const uint4* cf = (const uint4*)&Cb[w][0];
        uint4* gout = (uint4*)(hcurb + (size_t)base * HC);
        gout[lane] = cf[lane];
        gout[64 + lane] = cf[64 + lane];
        __builtin_amdgcn_wave_barrier();
    }
}

// ---------------- fused edge pipeline ----------------
// One wave per dst node. Slot reduction via LDS transpose (2 ds_write_b128
// + 8 ds_read_b32 per lane) instead of the 27-op shuffle butterfly — the
// DS pipe (~5.8 cyc/op) was the epilogue bottleneck. ssum keeps a 3-shfl
// reduce. Non-LAST: NW=1 (measured best). LAST: block b does only nodes
// 4b/4b+1 then out[b] = dot.
template <int NW, bool LAST>
__global__ void k_edge(const int* __restrict__ rowstart, const int* __restrict__ packed,
                       const float* __restrict__ ssrc, const float* __restrict__ sdst,
                       const float* __restrict__ escore_l,   // [5][2]
                       const unsigned short* __restrict__ hcurb, // [N][64] bf16
                       const float* __restrict__ eemb_l,     // [5][64]
                       const float* __restrict__ bias_l,     // [64]
                       unsigned short* __restrict__ actnext, float* __restrict__ out) {
    __shared__ float chbuf[NW][512];      // [slot][channel] partials, 2 KB/wave
    __shared__ float obuf[2][64];
    int w = threadIdx.x >> 6;
    int n = LAST ? (blockIdx.x * 4 + w) : (blockIdx.x * NW + w);
    int lane = threadIdx.x & 63;
    int sub = lane >> 3;
    int q   = lane & 7;
    int h   = q >> 2;

    int beg = rowstart[n];
    int end = rowstart[n + 1];
    float sd = sdst[n * 2 + h];

    float4 a0 = make_float4(0.f, 0.f, 0.f, 0.f);
    float4 a1 = make_float4(0.f, 0.f, 0.f, 0.f);
    float ssum = 0.f;
    for (int i = beg + sub; i < end; i += 8) {
        int p = packed[i];
        int s = p & 0x1FFFF;
        int a = (p >> 17) & 7;
        float lg = sd + ssrc[s * 2 + h] + escore_l[a * 2 + h];
        lg = lg >= 0.f ? lg : 0.2f * lg;
        float wt = __expf(lg);
        uint4 hv = *(const uint4*)(hcurb + (size_t)s * HC + q * 8);
        const float4* ep = (const float4*)(eemb_l + a * HC + q * 8);
        float4 e0 = ep[0], e1 = ep[1];
        a0.x += wt * (bf_lo(hv.x) + e0.x);
        a0.y += wt * (bf_hi(hv.x) + e0.y);
        a0.z += wt * (bf_lo(hv.y) + e0.z);
        a0.w += wt * (bf_hi(hv.y) + e0.w);
        a1.x += wt * (bf_lo(hv.z) + e1.x);
        a1.y += wt * (bf_hi(hv.z) + e1.y);
        a1.z += wt * (bf_lo(hv.w) + e1.z);
        a1.w += wt * (bf_hi(hv.w) + e1.w);
        ssum += wt;
    }
    // slot partials -> LDS (contiguous 1 KB per half: conflict-optimal)
    ((float4*)&chbuf[w][sub * 64 + q * 8])[0] = a0;
    ((float4*)&chbuf[w][sub * 64 + q * 8])[1] = a1;
    // ssum: 3-round butterfly (slots share q -> per-head totals), then pick
    // the head of CHANNEL `lane` (= lane>>5) from lane q=0 (head0)/q=4 (head1).
    for (int off = 8; off < 64; off <<= 1) ssum += __shfl_xor(ssum, off, 64);
    float ssum_h = __shfl(ssum, (lane >> 5) * 4, 64);
    float inv = 1.f / (ssum_h + 1e-16f);
    __builtin_amdgcn_wave_barrier();            // DS ops in-order per wave
    // transpose-reduce: lane = channel; 8 reads, 2-way bank aliasing (free)
    float s = 0.f;
    #pragma unroll
    for (int k = 0; k < 8; ++k) s += chbuf[w][k * 64 + lane];
    float v = s * inv + bias_l[lane];
    float o = v > 0.f ? v : (__expf(v) - 1.f);
    if (!LAST) {
        actnext[(size_t)n * HC + lane] = f2bf(o);
    } else {
        obuf[w][lane] = o;                      // w=0: user 4b, w=1: item 4b+1
        __syncthreads();
        if (w == 0) {
            float p = obuf[0][lane] * obuf[1][lane];
            for (int off = 32; off > 0; off >>= 1) p += __shfl_down(p, off, 64);
            if (lane == 0) out[blockIdx.x] = p;
        }
    }
}

// ---------------- launch ----------------
extern "C" void kernel_launch(void* const* d_in, const int* in_sizes, int n_in,
                              void* d_out, int out_size, void* d_ws, size_t ws_size,
                              hipStream_t stream) {
    const float* x       = (const float*)d_in[0];   // [N,4]
    const float* W0      = (const float*)d_in[1];   // [4,64]
    const float* W13     = (const float*)d_in[2];   // [3,64,64]
    const float* eemb    = (const float*)d_in[3];   // [4,5,64]
    const float* att_src = (const float*)d_in[4];   // [4,2,32]
    const float* att_dst = (const float*)d_in[5];   // [4,2,32]
    const float* bias    = (const float*)d_in[6];   // [4,64]
    const int*   eidx    = (const int*)d_in[7];     // [2,E]
    const int*   eattr   = (const int*)d_in[8];     // [E]
    float* out = (float*)d_out;

    const int* src = eidx;
    const int* dst = eidx + N_EDGES;

    char* wsb = (char*)d_ws;
    size_t off = 0;
    auto alloc = [&](size_t bytes) { char* p = wsb + off; off += (bytes + 255) & ~(size_t)255; return p; };
    unsigned short* hcurb  = (unsigned short*)alloc((size_t)N_NODES * HC * 2);
    unsigned short* actB   = (unsigned short*)alloc((size_t)N_NODES * HC * 2);
    float*          ssrc   = (float*)alloc((size_t)N_NODES * 2 * 4);
    float*          sdst   = (float*)alloc((size_t)N_NODES * 2 * 4);
    float*          escore = (float*)alloc(NLAYERS * ECLS * NHEADS * 4);
    int*            bh     = (int*)alloc((size_t)NBUCK * NBLK * 4);
    int*            bbase  = (int*)alloc((size_t)NBUCK * NBLK * 4);
    int*            part   = (int*)alloc(256 * 4);
    int*            rowstart = (int*)alloc(((size_t)N_NODES + 1) * 4);
    int*            bkt    = (int*)alloc((size_t)N_EDGES * 4);
    int*            packed = (int*)alloc((size_t)N_EDGES * 4);

    // ---- CSR build P1 + layer-0 linear (merged) ----
    k_chist_lin0<<<NBLK + LIN0_BLOCKS, 256, 0, stream>>>(
        dst, bh, x, W0, att_src, att_dst, hcurb, ssrc, sdst);
    k_s1<<<NBUCK, NBLK, 0, stream>>>(bh, bbase, part);
    k_s2<<<1, 256, 0, stream>>>(part, eemb, att_src, escore);
    k_cscatter<<<NBLK, 256, 0, stream>>>(src, dst, eattr, bbase, part, bkt);
    k_fine<<<NBUCK, 512, 0, stream>>>(part, bkt, packed, rowstart);

    for (int l = 0; l < NLAYERS; ++l) {
        if (l > 0) {
            k_linmfma<<<512, 256, 0, stream>>>(
                actB, W13 + (size_t)(l - 1) * HC * HC,
                att_src + l * HC, att_dst + l * HC, hcurb, ssrc, sdst);
        }
        const float* esl = escore + l * ECLS * NHEADS;
        const float* el  = eemb + (size_t)l * ECLS * HC;
        const float* bl  = bias + l * HC;
        if (l < NLAYERS - 1)
            k_edge<1, false><<<N_NODES, 64, 0, stream>>>(
                rowstart, packed, ssrc, sdst, esl, hcurb, el, bl, actB, nullptr);
        else
            k_edge<2, true><<<N_NODES / 4, 128, 0, stream>>>(
                rowstart, packed, ssrc, sdst, esl, hcurb, el, bl, nullptr, out);
    }
}

// Round 19
// 319.606 us; speedup vs baseline: 1.0833x; 1.0027x over previous
//
#include <hip/hip_runtime.h>
#include <hip/hip_bf16.h>
#include <math.h>

#define N_NODES 100000
#define N_EDGES 1600000
#define HC 64          // H*C
#define NHEADS 2
#define NLAYERS 4
#define ECLS 5
#define NBUCK 196              // ceil(N / 512); bucket = dst >> 9
#define NBLK 512               // coarse pass blocks
#define EPB (N_EDGES / NBLK)   // 3125 edges per coarse block (exact)
#define NGRP (N_NODES / 16)    // 6250 16-node groups (exact)
#define LIN0_BLOCKS 1024
#define FCAP 12288             // k_fine LDS staging capacity (avg bucket ~8163)
#define CHS 68                 // chbuf slot stride (floats): conflict-free b128

typedef __attribute__((ext_vector_type(8))) short short8;
typedef __attribute__((ext_vector_type(4))) float floatx4;
union F8 { uint4 u; short8 s; };

// bf16 (stored as ushort) -> f32
__device__ inline float bf_lo(unsigned int u) { return __uint_as_float(u << 16); }
__device__ inline float bf_hi(unsigned int u) { return __uint_as_float(u & 0xffff0000u); }
// f32 -> bf16 bits, round-to-nearest-even
__device__ inline unsigned short f2bf(float f) {
    unsigned int u = __float_as_uint(f);
    u += 0x7FFFu + ((u >> 16) & 1u);
    return (unsigned short)(u >> 16);
}

// ---------------- CSR P1 + layer-0 linear + escore (merged) ----------------
// Blocks [0,NBLK): per-(bucket,block) histogram. [NBLK, NBLK+LIN0): lin0.
// Block NBLK+LIN0: escore table (40 dots).
__global__ void k_chist_lin0(const int* __restrict__ dst, int* __restrict__ bh,
                             const float* __restrict__ in,
                             const float* __restrict__ W,        // [4][64]
                             const float* __restrict__ asrc, const float* __restrict__ adst,
                             unsigned short* __restrict__ hcurb,
                             float* __restrict__ ssrc, float* __restrict__ sdst,
                             const float* __restrict__ eemb, float* __restrict__ escore) {
    int tid = threadIdx.x;
    if (blockIdx.x < NBLK) {
        __shared__ int lh[NBUCK];
        int blk = blockIdx.x;
        for (int i = tid; i < NBUCK; i += 256) lh[i] = 0;
        __syncthreads();
        int s = blk * EPB;
        for (int i = tid; i < EPB; i += 256) atomicAdd(&lh[dst[s + i] >> 9], 1);
        __syncthreads();
        for (int i = tid; i < NBUCK; i += 256) bh[i * NBLK + blk] = lh[i];
        return;
    }
    if (blockIdx.x >= NBLK + LIN0_BLOCKS) {
        if (tid < NLAYERS * ECLS * NHEADS) {
            int l = tid / (ECLS * NHEADS);
            int r = tid % (ECLS * NHEADS);
            int c = r >> 1;
            int h = r & 1;
            float s = 0.f;
            const float* ev = eemb + l * ECLS * HC + c * HC + h * 32;
            const float* av = asrc + l * HC + h * 32;   // att_src base passed
            for (int k = 0; k < 32; ++k) s += ev[k] * av[k];
            escore[tid] = s;
        }
        return;
    }
    int j = tid & 63;
    int wid = ((blockIdx.x - NBLK) * 256 + tid) >> 6;
    int nwaves = LIN0_BLOCKS * 4;

    float w0 = W[0 * HC + j], w1 = W[1 * HC + j], w2 = W[2 * HC + j], w3 = W[3 * HC + j];
    int head = j >> 5;
    int c = j & 31;
    float as = asrc[head * 32 + c];
    float ad = adst[head * 32 + c];

    for (int n = wid; n < N_NODES; n += nwaves) {
        int nu = __builtin_amdgcn_readfirstlane(n);
        float4 r = *(const float4*)(in + (size_t)nu * 4);
        float acc = r.x * w0 + r.y * w1 + r.z * w2 + r.w * w3;
        hcurb[(size_t)nu * HC + j] = f2bf(acc);
        float ps = acc * as;
        float pd = acc * ad;
        for (int off = 16; off > 0; off >>= 1) {
            ps += __shfl_down(ps, off, 32);
            pd += __shfl_down(pd, off, 32);
        }
        if (c == 0) {
            ssrc[nu * 2 + head] = ps;
            sdst[nu * 2 + head] = pd;
        }
    }
}

// P2a: per-bucket exclusive scan of the NBLK per-block counts; raw bucket
// sums to part[] (consumers scan part locally — no k_s2 dispatch).
__global__ void k_s1(const int* __restrict__ bh, int* __restrict__ bbase,
                     int* __restrict__ part) {
    __shared__ int tmp[NBLK];
    int tid = threadIdx.x;
    int i = blockIdx.x * NBLK + tid;
    int v = bh[i];
    tmp[tid] = v;
    __syncthreads();
    for (int off = 1; off < NBLK; off <<= 1) {
        int t = (tid >= off) ? tmp[tid - off] : 0;
        __syncthreads();
        tmp[tid] += t;
        __syncthreads();
    }
    bbase[i] = tmp[tid] - v;
    if (tid == NBLK - 1) part[blockIdx.x] = tmp[NBLK - 1];
}

// P3: coarse scatter, LDS-STAGED -> coalesced global writes.
// part[] holds raw bucket sums; scan locally.
__global__ void k_cscatter(const int* __restrict__ src, const int* __restrict__ dst,
                           const int* __restrict__ attr, const int* __restrict__ bbase,
                           const int* __restrict__ part, int* __restrict__ bkt) {
    __shared__ int tmp[256];
    __shared__ int cur[NBUCK];
    __shared__ int gadj[NBUCK];
    __shared__ int stage[EPB];            // 12.5 KB
    __shared__ unsigned char stb[EPB];    // 3.1 KB
    int tid = threadIdx.x, blk = blockIdx.x;
    // local exclusive scan of part -> gadj (bucket global base)
    int pv = (tid < NBUCK) ? part[tid] : 0;
    tmp[tid] = pv;
    __syncthreads();
    for (int off = 1; off < 256; off <<= 1) {
        int t = (tid >= off) ? tmp[tid - off] : 0;
        __syncthreads();
        tmp[tid] += t;
        __syncthreads();
    }
    if (tid < NBUCK) gadj[tid] = tmp[tid] - pv;
    if (tid < NBUCK) cur[tid] = 0;
    for (int i = tid + 256; i < NBUCK; i += 256) cur[i] = 0;  // (NBUCK<256: no-op)
    __syncthreads();
    int s0 = blk * EPB;
    for (int i = tid; i < EPB; i += 256) atomicAdd(&cur[dst[s0 + i] >> 9], 1);
    __syncthreads();
    int v = (tid < NBUCK) ? cur[tid] : 0;
    tmp[tid] = v;
    __syncthreads();
    for (int off = 1; off < 256; off <<= 1) {
        int t = (tid >= off) ? tmp[tid - off] : 0;
        __syncthreads();
        tmp[tid] += t;
        __syncthreads();
    }
    int ex = tmp[tid] - v;
    if (tid < NBUCK) {
        cur[tid] = ex;                                         // local cursor
        gadj[tid] += bbase[tid * NBLK + blk] - ex;             // global - local
    }
    __syncthreads();
    for (int i = tid; i < EPB; i += 256) {
        int e = s0 + i;
        int d = dst[e];
        int b = d >> 9;
        int pos = atomicAdd(&cur[b], 1);
        stage[pos] = src[e] | (attr[e] << 17) | ((d & 511) << 20);
        stb[pos] = (unsigned char)b;
    }
    __syncthreads();
    for (int i = tid; i < EPB; i += 256)
        bkt[gadj[stb[i]] + i] = stage[i];
}

// P4: fine sort within each bucket, LDS-STAGED (fallback if > FCAP).
// part[] raw; local inclusive scan for [base, bend).
__global__ void k_fine(const int* __restrict__ part, const int* __restrict__ bkt,
                       int* __restrict__ packed, int* __restrict__ rowstart) {
    __shared__ int hist[512];
    __shared__ int cur[512];
    __shared__ int pscan[512];
    __shared__ int stage[FCAP];           // 48 KB
    int b = blockIdx.x, tid = threadIdx.x;   // 512 threads
    int pv = (tid < NBUCK) ? part[tid] : 0;
    pscan[tid] = pv;
    __syncthreads();
    for (int off = 1; off < 512; off <<= 1) {
        int t = (tid >= off) ? pscan[tid - off] : 0;
        __syncthreads();
        pscan[tid] += t;
        __syncthreads();
    }
    int base = (b == 0) ? 0 : pscan[b - 1];
    int bend = pscan[b];
    int nb = bend - base;
    hist[tid] = 0;
    __syncthreads();
    for (int i = tid; i < nb; i += 512)
        atomicAdd(&hist[(bkt[base + i] >> 20) & 0x1FF], 1);
    __syncthreads();
    int v = hist[tid];
    for (int off = 1; off < 512; off <<= 1) {
        int t = (tid >= off) ? hist[tid - off] : 0;
        __syncthreads();
        hist[tid] += t;
        __syncthreads();
    }
    int excl = hist[tid] - v;
    int node = (b << 9) + tid;
    if (node <= N_NODES) rowstart[node] = base + excl;
    cur[tid] = excl;
    __syncthreads();
    if (nb <= FCAP) {
        for (int i = tid; i < nb; i += 512) {
            int p = bkt[base + i];
            int r = atomicAdd(&cur[(p >> 20) & 0x1FF], 1);
            stage[r] = p;
        }
        __syncthreads();
        for (int i = tid; i < nb; i += 512) packed[base + i] = stage[i];
    } else {
        for (int i = tid; i < nb; i += 512) {
            int p = bkt[base + i];
            int r = atomicAdd(&cur[(p >> 20) & 0x1FF], 1);
            packed[base + r] = p;
        }
    }
}

// ---------------- MFMA linear (layers 1..3) ----------------
__global__ void k_linmfma(const unsigned short* __restrict__ actB,
                          const float* __restrict__ Wl,       // [64][64] fp32
                          const float* __restrict__ asrc,     // [64]
                          const float* __restrict__ adst,     // [64]
                          unsigned short* __restrict__ hcurb,
                          float* __restrict__ ssrc, float* __restrict__ sdst) {
    __shared__ uint4 WB[512];
    __shared__ unsigned short Cb[4][1024];
    int tid = threadIdx.x;
    int lane = tid & 63;
    int w = tid >> 6;
    int q = lane >> 4;
    int c = lane & 15;

    for (int rid = tid; rid < 512; rid += 256) {
        int kk = rid >> 8;
        int t  = (rid >> 6) & 3;
        int ln = rid & 63;
        int qq = ln >> 4, cc = ln & 15;
        unsigned int u[4];
        #pragma unroll
        for (int jj = 0; jj < 4; ++jj) {
            float v0 = Wl[(kk * 32 + qq * 8 + jj * 2 + 0) * 64 + 16 * t + cc];
            float v1 = Wl[(kk * 32 + qq * 8 + jj * 2 + 1) * 64 + 16 * t + cc];
            u[jj] = (unsigned int)f2bf(v0) | ((unsigned int)f2bf(v1) << 16);
        }
        WB[rid] = make_uint4(u[0], u[1], u[2], u[3]);
    }
    __syncthreads();

    short8 bfr[2][4];
    #pragma unroll
    for (int kk = 0; kk < 2; ++kk)
        #pragma unroll
        for (int t = 0; t < 4; ++t) {
            F8 tmp; tmp.u = WB[(kk * 4 + t) * 64 + lane];
            bfr[kk][t] = tmp.s;
        }

    float as_[4], ad_[4];
    #pragma unroll
    for (int t = 0; t < 4; ++t) {
        as_[t] = asrc[16 * t + c];
        ad_[t] = adst[16 * t + c];
    }

    int wid = (blockIdx.x * 256 + tid) >> 6;
    int nwaves = gridDim.x * 4;

    for (int g = wid; g < NGRP; g += nwaves) {
        int base = g * 16;
        F8 a0, a1;
        a0.u = *(const uint4*)(actB + (size_t)(base + c) * HC + q * 8);
        a1.u = *(const uint4*)(actB + (size_t)(base + c) * HC + 32 + q * 8);

        floatx4 acc[4];
        #pragma unroll
        for (int t = 0; t < 4; ++t) {
            acc[t] = (floatx4){0.f, 0.f, 0.f, 0.f};
            acc[t] = __builtin_amdgcn_mfma_f32_16x16x32_bf16(a0.s, bfr[0][t], acc[t], 0, 0, 0);
            acc[t] = __builtin_amdgcn_mfma_f32_16x16x32_bf16(a1.s, bfr[1][t], acc[t], 0, 0, 0);
        }

        #pragma unroll
        for (int r = 0; r < 4; ++r) {
            float h0s = acc[0][r] * as_[0] + acc[1][r] * as_[1];
            float h1s = acc[2][r] * as_[2] + acc[3][r] * as_[3];
            float h0d = acc[0][r] * ad_[0] + acc[1][r] * ad_[1];
            float h1d = acc[2][r] * ad_[2] + acc[3][r] * ad_[3];
            #pragma unroll
            for (int off = 1; off < 16; off <<= 1) {
                h0s += __shfl_xor(h0s, off, 64);
                h1s += __shfl_xor(h1s, off, 64);
                h0d += __shfl_xor(h0d, off, 64);
                h1d += __shfl_xor(h1d, off, 64);
            }
            if (c == 0) {
                int node = base + q * 4 + r;
                *(float2*)(ssrc + node * 2) = make_float2(h0s, h1s);
                *(float2*)(sdst + node * 2) = make_float2(h0d, h1d);
            }
        }

        #pragma unroll
        for (int t = 0; t < 4; ++t)
            #pragma unroll
            for (int r = 0; r < 4; ++r)
                Cb[w][(q * 4 + r) * 64 + 16 * t + c] = f2bf(acc[t][r]);
        __builtin_amdgcn_wave_barrier();
        const uint4* cf = (const uint4*)&Cb[w][0];
        uint4* gout = (uint4*)(hcurb + (size_t)base * HC);
        gout[lane] = cf[lane];
        gout[64 + lane] = cf[64 + lane];
        __builtin_amdgcn_wave_barrier();
    }
}

// ---------------- fused edge pipeline ----------------
// One wave per dst node. Slot reduction via LDS transpose. chbuf slot
// stride = 68 floats (272 B, 16B-aligned): write bank = (sub*4+q*8+j)%32
// -> 8 accesses/bank = the b128 floor (stride 64 was 16/bank -> 1.6M
// conflicts). Reads: (4k+lane)%32 -> 2-way (free).
template <int NW, bool LAST>
__global__ void k_edge(const int* __restrict__ rowstart, const int* __restrict__ packed,
                       const float* __restrict__ ssrc, const float* __restrict__ sdst,
                       const float* __restrict__ escore_l,   // [5][2]
                       const unsigned short* __restrict__ hcurb, // [N][64] bf16
                       const float* __restrict__ eemb_l,     // [5][64]
                       const float* __restrict__ bias_l,     // [64]
                       unsigned short* __restrict__ actnext, float* __restrict__ out) {
    __shared__ float chbuf[NW][8 * CHS];  // [slot][channel] partials
    __shared__ float obuf[2][64];
    int w = threadIdx.x >> 6;
    int n = LAST ? (blockIdx.x * 4 + w) : (blockIdx.x * NW + w);
    int lane = threadIdx.x & 63;
    int sub = lane >> 3;
    int q   = lane & 7;
    int h   = q >> 2;

    int beg = rowstart[n];
    int end = rowstart[n + 1];
    float sd = sdst[n * 2 + h];

    float4 a0 = make_float4(0.f, 0.f, 0.f, 0.f);
    float4 a1 = make_float4(0.f, 0.f, 0.f, 0.f);
    float ssum = 0.f;
    for (int i = beg + sub; i < end; i += 8) {
        int p = packed[i];
        int s = p & 0x1FFFF;
        int a = (p >> 17) & 7;
        float lg = sd + ssrc[s * 2 + h] + escore_l[a * 2 + h];
        lg = lg >= 0.f ? lg : 0.2f * lg;
        float wt = __expf(lg);
        uint4 hv = *(const uint4*)(hcurb + (size_t)s * HC + q * 8);
        const float4* ep = (const float4*)(eemb_l + a * HC + q * 8);
        float4 e0 = ep[0], e1 = ep[1];
        a0.x += wt * (bf_lo(hv.x) + e0.x);
        a0.y += wt * (bf_hi(hv.x) + e0.y);
        a0.z += wt * (bf_lo(hv.y) + e0.z);
        a0.w += wt * (bf_hi(hv.y) + e0.w);
        a1.x += wt * (bf_lo(hv.z) + e1.x);
        a1.y += wt * (bf_hi(hv.z) + e1.y);
        a1.z += wt * (bf_lo(hv.w) + e1.z);
        a1.w += wt * (bf_hi(hv.w) + e1.w);
        ssum += wt;
    }
    // slot partials -> LDS (stride-68: conflict floor for b128)
    ((float4*)&chbuf[w][sub * CHS + q * 8])[0] = a0;
    ((float4*)&chbuf[w][sub * CHS + q * 8])[1] = a1;
    // ssum: 3-round butterfly, then pick head of CHANNEL `lane` (= lane>>5)
    for (int off = 8; off < 64; off <<= 1) ssum += __shfl_xor(ssum, off, 64);
    float ssum_h = __shfl(ssum, (lane >> 5) * 4, 64);
    float inv = 1.f / (ssum_h + 1e-16f);
    __builtin_amdgcn_wave_barrier();            // DS ops in-order per wave
    float s = 0.f;
    #pragma unroll
    for (int k = 0; k < 8; ++k) s += chbuf[w][k * CHS + lane];
    float v = s * inv + bias_l[lane];
    float o = v > 0.f ? v : (__expf(v) - 1.f);
    if (!LAST) {
        actnext[(size_t)n * HC + lane] = f2bf(o);
    } else {
        obuf[w][lane] = o;                      // w=0: user 4b, w=1: item 4b+1
        __syncthreads();
        if (w == 0) {
            float p = obuf[0][lane] * obuf[1][lane];
            for (int off = 32; off > 0; off >>= 1) p += __shfl_down(p, off, 64);
            if (lane == 0) out[blockIdx.x] = p;
        }
    }
}

// ---------------- launch ----------------
extern "C" void kernel_launch(void* const* d_in, const int* in_sizes, int n_in,
                              void* d_out, int out_size, void* d_ws, size_t ws_size,
                              hipStream_t stream) {
    const float* x       = (const float*)d_in[0];   // [N,4]
    const float* W0      = (const float*)d_in[1];   // [4,64]
    const float* W13     = (const float*)d_in[2];   // [3,64,64]
    const float* eemb    = (const float*)d_in[3];   // [4,5,64]
    const float* att_src = (const float*)d_in[4];   // [4,2,32]
    const float* att_dst = (const float*)d_in[5];   // [4,2,32]
    const float* bias    = (const float*)d_in[6];   // [4,64]
    const int*   eidx    = (const int*)d_in[7];     // [2,E]
    const int*   eattr   = (const int*)d_in[8];     // [E]
    float* out = (float*)d_out;

    const int* src = eidx;
    const int* dst = eidx + N_EDGES;

    char* wsb = (char*)d_ws;
    size_t off = 0;
    auto alloc = [&](size_t bytes) { char* p = wsb + off; off += (bytes + 255) & ~(size_t)255; return p; };
    unsigned short* hcurb  = (unsigned short*)alloc((size_t)N_NODES * HC * 2);
    unsigned short* actB   = (unsigned short*)alloc((size_t)N_NODES * HC * 2);
    float*          ssrc   = (float*)alloc((size_t)N_NODES * 2 * 4);
    float*          sdst   = (float*)alloc((size_t)N_NODES * 2 * 4);
    float*          escore = (float*)alloc(NLAYERS * ECLS * NHEADS * 4);
    int*            bh     = (int*)alloc((size_t)NBUCK * NBLK * 4);
    int*            bbase  = (int*)alloc((size_t)NBUCK * NBLK * 4);
    int*            part   = (int*)alloc(256 * 4);
    int*            rowstart = (int*)alloc(((size_t)N_NODES + 1) * 4);
    int*            bkt    = (int*)alloc((size_t)N_EDGES * 4);
    int*            packed = (int*)alloc((size_t)N_EDGES * 4);

    // ---- CSR build P1 + layer-0 linear + escore (merged) ----
    k_chist_lin0<<<NBLK + LIN0_BLOCKS + 1, 256, 0, stream>>>(
        dst, bh, x, W0, att_src, att_dst, hcurb, ssrc, sdst, eemb, escore);
    k_s1<<<NBUCK, NBLK, 0, stream>>>(bh, bbase, part);
    k_cscatter<<<NBLK, 256, 0, stream>>>(src, dst, eattr, bbase, part, bkt);
    k_fine<<<NBUCK, 512, 0, stream>>>(part, bkt, packed, rowstart);

    for (int l = 0; l < NLAYERS; ++l) {
        if (l > 0) {
            k_linmfma<<<512, 256, 0, stream>>>(
                actB, W13 + (size_t)(l - 1) * HC * HC,
                att_src + l * HC, att_dst + l * HC, hcurb, ssrc, sdst);
        }
        const float* esl = escore + l * ECLS * NHEADS;
        const float* el  = eemb + (size_t)l * ECLS * HC;
        const float* bl  = bias + l * HC;
        if (l < NLAYERS - 1)
            k_edge<1, false><<<N_NODES, 64, 0, stream>>>(
                rowstart, packed, ssrc, sdst, esl, hcurb, el, bl, actB, nullptr);
        else
            k_edge<2, true><<<N_NODES / 4, 128, 0, stream>>>(
                rowstart, packed, ssrc, sdst, esl, hcurb, el, bl, nullptr, out);
    }
}